// Round 2
// baseline (202.500 us; speedup 1.0000x reference)
//
#include <hip/hip_runtime.h>

#define NN 10000    // nodes
#define RR 100      // relations
#define EE 5000     // edges per relation
#define D0 2048
#define D1 128
#define D2 64
#define D3 20
#define NE (RR*EE)  // 500000 edges total

using short8  = __attribute__((ext_vector_type(8))) short;
using float4e = __attribute__((ext_vector_type(4))) float;

__device__ __forceinline__ unsigned short f2bf(float f) {
  unsigned int u = __float_as_uint(f);
  unsigned int r = u + 0x7fffu + ((u >> 16) & 1u);   // RNE
  return (unsigned short)(r >> 16);
}
__device__ __forceinline__ float bf2f(unsigned short u) {
  return __uint_as_float(((unsigned int)u) << 16);
}
__device__ __forceinline__ unsigned int pk2(float lo, float hi) {
  return ((unsigned int)f2bf(hi) << 16) | (unsigned int)f2bf(lo);
}

// ---------------------------------------------------------------------------
// CSR build
// ---------------------------------------------------------------------------
// Replaces hipMemsetAsync(deg, 0, 4MB): the rocclr fillBufferAligned kernel
// ran at 46 us/launch inside the captured graph (latency-bound tiny grid).
// 250,000 int4 stores across 977 blocks runs at HBM write BW (~2 us).
__global__ void zero_deg_kernel(int4* __restrict__ deg4) {
  int i = blockIdx.x * 256 + threadIdx.x;
  if (i < (NN * RR) / 4) deg4[i] = make_int4(0, 0, 0, 0);
}

__global__ void deg_kernel(const int* __restrict__ ei, int* __restrict__ deg) {
  int gid = blockIdx.x * 256 + threadIdx.x;
  if (gid >= NE) return;
  int r = gid / EE, e = gid - r * EE;
  int d = ei[r * 2 * EE + EE + e];
  atomicAdd(&deg[r * NN + d], 1);
}

__global__ void cnt_kernel(const int* __restrict__ deg, int* __restrict__ cnt) {
  int n = blockIdx.x * 256 + threadIdx.x;
  if (n >= NN) return;
  int s = 0;
  for (int r = 0; r < RR; r++) s += deg[r * NN + n];
  cnt[n] = s;
}

__global__ __launch_bounds__(1024) void scan_kernel(const int* __restrict__ cnt,
                                                    int* __restrict__ off,
                                                    int* __restrict__ cur) {
  __shared__ int wsum[16];
  __shared__ int carry_s;
  const int tid = threadIdx.x;
  const int wv = tid >> 6, lane = tid & 63;
  if (tid == 0) carry_s = 0;
  __syncthreads();
  for (int base = 0; base < NN; base += 1024) {
    int i = base + tid;
    int v = (i < NN) ? cnt[i] : 0;
    int s = v;
#pragma unroll
    for (int d = 1; d < 64; d <<= 1) {
      int t = __shfl_up(s, d, 64);
      if (lane >= d) s += t;
    }
    if (lane == 63) wsum[wv] = s;
    __syncthreads();
    if (wv == 0) {
      int w = (lane < 16) ? wsum[lane] : 0;
#pragma unroll
      for (int d = 1; d < 16; d <<= 1) {
        int t = __shfl_up(w, d, 64);
        if (lane >= d) w += t;
      }
      if (lane < 16) wsum[lane] = w;
    }
    __syncthreads();
    int excl = carry_s + (wv > 0 ? wsum[wv - 1] : 0) + s - v;
    if (i < NN) { off[i] = excl; cur[i] = excl; }
    __syncthreads();
    if (tid == 1023) carry_s += wsum[15];
    __syncthreads();
  }
  if (tid == 0) off[NN] = carry_s;
}

// rec = (r<<14)|src, esc = 1/max(deg,1)
__global__ void scatter_kernel(const int* __restrict__ ei,
                               const int* __restrict__ deg,
                               int* __restrict__ cur, int* __restrict__ rec,
                               float* __restrict__ esc) {
  int gid = blockIdx.x * 256 + threadIdx.x;
  if (gid >= NE) return;
  int r = gid / EE, e = gid - r * EE;
  int s = ei[r * 2 * EE + e];
  int d = ei[r * 2 * EE + EE + e];
  int p = atomicAdd(&cur[d], 1);
  rec[p] = (r << 14) | s;
  esc[p] = 1.0f / fmaxf((float)deg[r * NN + d], 1.0f);
}

// ---------------------------------------------------------------------------
// weight prep (bf16, transposed [n][k] for MFMA B-frag loads)
// ---------------------------------------------------------------------------
__global__ void wtrans_kernel(const float* __restrict__ W,
                              unsigned short* __restrict__ Bt) {
  int idx = blockIdx.x * 256 + threadIdx.x;
  if (idx >= 128 * 2048) return;
  int n = idx >> 11, k = idx & 2047;
  Bt[idx] = f2bf(W[(size_t)k * 128 + n]);
}

__global__ void wc1t_kernel(const float* __restrict__ root1,
                            const float* __restrict__ basis1,
                            unsigned short* __restrict__ Wt) {
  int idx = blockIdx.x * 256 + threadIdx.x;
  if (idx >= 64 * 1152) return;
  int o = idx / 1152, j = idx - o * 1152;
  float v = (j < 128) ? root1[j * 64 + o] : basis1[(j - 128) * 64 + o];
  Wt[idx] = f2bf(v);
}

__global__ void wc2t_kernel(const float* __restrict__ root2,
                            const float* __restrict__ basis2,
                            unsigned short* __restrict__ Wt) {
  int idx = blockIdx.x * 256 + threadIdx.x;
  if (idx >= 32 * 576) return;
  int c = idx / 576, j = idx - c * 576;
  float v = 0.f;
  if (c < 20) v = (j < 64) ? root2[j * 20 + c] : basis2[(j - 64) * 20 + c];
  Wt[idx] = f2bf(v);
}

// ---------------------------------------------------------------------------
// gemm0: xp[ks] = x_drug[:, ks*512:+512] @ drug_w[ks*512:,:]  (K-split 4)
// bf16 MFMA 16x16x32; tile M=32, N=128, BK=64; double-buffered XOR-swizzled
// LDS; ONE barrier per K-step (T3 minimum pipeline). grid = dim3(313,4) =
// 1252 blocks (~4.9 blocks/CU).
// ---------------------------------------------------------------------------
__global__ __launch_bounds__(256) void gemm0_mfma(
    const float* __restrict__ A, const unsigned short* __restrict__ Btw,
    float* __restrict__ xp) {
  __shared__ __align__(16) unsigned short Asb[2][32 * 64];    // 2 x 4 KB
  __shared__ __align__(16) unsigned short Bsb[2][128 * 64];   // 2 x 16 KB
  const int tid = threadIdx.x;
  const int m0 = blockIdx.x * 32;
  const int ks = blockIdx.y;
  const int wv = tid >> 6, lane = tid & 63;
  const int lrow = lane & 15, quad = lane >> 4;
  const int mt = wv >> 1;           // which 16-row half of the 32-row tile
  const int nh = (wv & 1) * 4;      // 4 n-tiles of 16 cols (64-col half)

  const int ar = tid >> 3, ag = tid & 7;
  int gra = m0 + ar; if (gra >= NN) gra = NN - 1;
  const float* Ap = &A[(size_t)gra * D0 + ks * 512 + ag * 4];
  const int asw = (ar & 7) << 4;
  const int aw0 = (ar * 128 + ((ag * 8) ^ asw)) >> 1;        // ushort idx
  const int aw1 = (ar * 128 + ((64 + ag * 8) ^ asw)) >> 1;

  const int br = tid >> 1, bh = tid & 1;
  const unsigned short* Bp = &Btw[(size_t)br * D0 + ks * 512 + bh * 8];
  const int bsw = (br & 7) << 4;
  int bw[4];
#pragma unroll
  for (int j = 0; j < 4; j++)
    bw[j] = (br * 128 + ((bh * 16 + j * 32) ^ bsw)) >> 1;

  float4 a0, a1;
  uint4 b0, b1, b2, b3;

#define G0_LOADG(c)                                  \
  { a0 = *(const float4*)(Ap + (c) * 64);            \
    a1 = *(const float4*)(Ap + (c) * 64 + 32);       \
    b0 = *(const uint4*)(Bp + (c) * 64);             \
    b1 = *(const uint4*)(Bp + (c) * 64 + 16);        \
    b2 = *(const uint4*)(Bp + (c) * 64 + 32);        \
    b3 = *(const uint4*)(Bp + (c) * 64 + 48); }

#define G0_STOREL(buf)                                                  \
  { uint2 p0, p1;                                                       \
    p0.x = pk2(a0.x, a0.y); p0.y = pk2(a0.z, a0.w);                     \
    p1.x = pk2(a1.x, a1.y); p1.y = pk2(a1.z, a1.w);                     \
    *(uint2*)&Asb[buf][aw0] = p0;                                       \
    *(uint2*)&Asb[buf][aw1] = p1;                                       \
    *(uint4*)&Bsb[buf][bw[0]] = b0;                                     \
    *(uint4*)&Bsb[buf][bw[1]] = b1;                                     \
    *(uint4*)&Bsb[buf][bw[2]] = b2;                                     \
    *(uint4*)&Bsb[buf][bw[3]] = b3; }

#define G0_COMPUTE(buf)                                                 \
  { const int arow = mt * 16 + lrow;                                    \
    const int aswz = (arow & 7) << 4;                                   \
    _Pragma("unroll")                                                   \
    for (int kk = 0; kk < 2; kk++) {                                    \
      short8 af = *(const short8*)&Asb[buf][(arow * 128 + ((quad * 16 + kk * 64) ^ aswz)) >> 1]; \
      _Pragma("unroll")                                                 \
      for (int nt = 0; nt < 4; nt++) {                                  \
        const int brow = (nh + nt) * 16 + lrow;                         \
        short8 bfr = *(const short8*)&Bsb[buf][(brow * 128 + ((quad * 16 + kk * 64) ^ ((brow & 7) << 4))) >> 1]; \
        acc[nt] = __builtin_amdgcn_mfma_f32_16x16x32_bf16(af, bfr, acc[nt], 0, 0, 0); \
      }                                                                 \
    } }

  float4e acc[4];
#pragma unroll
  for (int i = 0; i < 4; i++) { acc[i][0]=0.f; acc[i][1]=0.f; acc[i][2]=0.f; acc[i][3]=0.f; }

  G0_LOADG(0);
  G0_STOREL(0);
  __syncthreads();

#pragma unroll
  for (int c = 0; c < 8; c++) {
    if (c < 7) G0_LOADG(c + 1);
    G0_COMPUTE(c & 1);
    if (c < 7) G0_STOREL((c + 1) & 1);
    __syncthreads();
  }

#pragma unroll
  for (int nt = 0; nt < 4; nt++) {
    const int col = (nh + nt) * 16 + lrow;
#pragma unroll
    for (int r = 0; r < 4; r++) {
      const int row = m0 + mt * 16 + quad * 4 + r;
      if (row < NN)
        xp[(size_t)ks * (NN * D1) + (size_t)row * D1 + col] = acc[nt][r];
    }
  }
}

// xb = bf16(xp0+xp1+xp2+xp3)
__global__ void reduce_kernel(const float* __restrict__ xp,
                              unsigned short* __restrict__ xb) {
  int idx = (blockIdx.x * 256 + threadIdx.x) * 4;
  if (idx >= NN * D1) return;
  float4 a = *(const float4*)&xp[idx];
  float4 b = *(const float4*)&xp[NN * D1 + idx];
  float4 c = *(const float4*)&xp[2 * NN * D1 + idx];
  float4 d = *(const float4*)&xp[3 * NN * D1 + idx];
  ushort4 o;
  o.x = f2bf(a.x + b.x + c.x + d.x); o.y = f2bf(a.y + b.y + c.y + d.y);
  o.z = f2bf(a.z + b.z + c.z + d.z); o.w = f2bf(a.w + b.w + c.w + d.w);
  *(ushort4*)&xb[idx] = o;
}

// ---------------------------------------------------------------------------
// agg1e: A1b[n, b*128+i] = bf16( sum_{e->n} esc_e*comp1[r_e,b]*x[src_e,i] )
// one wave per node; lane holds 2 of 128 channels; 4-edge unroll
// ---------------------------------------------------------------------------
__global__ __launch_bounds__(256) void agg1e_kernel(
    const unsigned short* __restrict__ xb, const int* __restrict__ off,
    const int* __restrict__ rec, const float* __restrict__ esc,
    const float* __restrict__ comp, unsigned short* __restrict__ A1b) {
  __shared__ float s_comp[RR * 8];
  const int tid = threadIdx.x;
  for (int i = tid; i < RR * 8; i += 256) s_comp[i] = comp[i];
  __syncthreads();
  const int wv = tid >> 6, lane = tid & 63;
  const int n = blockIdx.x * 4 + wv;
  if (n >= NN) return;
  float acc[8][2];
#pragma unroll
  for (int b = 0; b < 8; b++) { acc[b][0] = 0.f; acc[b][1] = 0.f; }
  const int beg = off[n], end = off[n + 1];
  int idx = beg;
  for (; idx + 3 < end; idx += 4) {
    int rc[4]; float sc[4]; unsigned int xv[4];
#pragma unroll
    for (int u = 0; u < 4; u++) {
      rc[u] = rec[idx + u];
      sc[u] = esc[idx + u];
    }
#pragma unroll
    for (int u = 0; u < 4; u++)
      xv[u] = *(const unsigned int*)&xb[(size_t)(rc[u] & 16383) * D1 + lane * 2];
#pragma unroll
    for (int u = 0; u < 4; u++) {
      const float* cb = &s_comp[(rc[u] >> 14) * 8];
      float x0 = __uint_as_float((xv[u] & 0xffffu) << 16);
      float x1 = __uint_as_float(xv[u] & 0xffff0000u);
#pragma unroll
      for (int b = 0; b < 8; b++) {
        float w = sc[u] * cb[b];
        acc[b][0] += w * x0;
        acc[b][1] += w * x1;
      }
    }
  }
  for (; idx < end; idx++) {
    int rc = rec[idx];
    float sc = esc[idx];
    unsigned int xv = *(const unsigned int*)&xb[(size_t)(rc & 16383) * D1 + lane * 2];
    const float* cb = &s_comp[(rc >> 14) * 8];
    float x0 = __uint_as_float((xv & 0xffffu) << 16);
    float x1 = __uint_as_float(xv & 0xffff0000u);
#pragma unroll
    for (int b = 0; b < 8; b++) {
      float w = sc * cb[b];
      acc[b][0] += w * x0;
      acc[b][1] += w * x1;
    }
  }
#pragma unroll
  for (int b = 0; b < 8; b++) {
    ushort2 o; o.x = f2bf(acc[b][0]); o.y = f2bf(acc[b][1]);
    *(ushort2*)&A1b[(size_t)n * 1024 + b * 128 + lane * 2] = o;
  }
}

// ---------------------------------------------------------------------------
// agg2e: A2b[n, b*64+i] = bf16( sum_{e->n} esc_e*comp2[r_e,b]*h[src_e,i] )
// ---------------------------------------------------------------------------
__global__ __launch_bounds__(256) void agg2e_kernel(
    const unsigned short* __restrict__ hb, const int* __restrict__ off,
    const int* __restrict__ rec, const float* __restrict__ esc,
    const float* __restrict__ comp, unsigned short* __restrict__ A2b) {
  __shared__ float s_comp[RR * 8];
  const int tid = threadIdx.x;
  for (int i = tid; i < RR * 8; i += 256) s_comp[i] = comp[i];
  __syncthreads();
  const int wv = tid >> 6, lane = tid & 63;
  const int n = blockIdx.x * 4 + wv;
  if (n >= NN) return;
  float acc[8];
#pragma unroll
  for (int b = 0; b < 8; b++) acc[b] = 0.f;
  const int beg = off[n], end = off[n + 1];
  int idx = beg;
  for (; idx + 3 < end; idx += 4) {
    int rc[4]; float sc[4]; float hv[4];
#pragma unroll
    for (int u = 0; u < 4; u++) {
      rc[u] = rec[idx + u];
      sc[u] = esc[idx + u];
    }
#pragma unroll
    for (int u = 0; u < 4; u++)
      hv[u] = bf2f(hb[(size_t)(rc[u] & 16383) * D2 + lane]);
#pragma unroll
    for (int u = 0; u < 4; u++) {
      const float* cb = &s_comp[(rc[u] >> 14) * 8];
#pragma unroll
      for (int b = 0; b < 8; b++) acc[b] += sc[u] * cb[b] * hv[u];
    }
  }
  for (; idx < end; idx++) {
    int rc = rec[idx];
    float sc = esc[idx];
    float hv = bf2f(hb[(size_t)(rc & 16383) * D2 + lane]);
    const float* cb = &s_comp[(rc >> 14) * 8];
#pragma unroll
    for (int b = 0; b < 8; b++) acc[b] += sc * cb[b] * hv;
  }
#pragma unroll
  for (int b = 0; b < 8; b++)
    A2b[(size_t)n * 512 + b * 64 + lane] = f2bf(acc[b]);
}

// ---------------------------------------------------------------------------
// hlayer: hb = bf16(relu([xb|A1b](K=1152) @ Wc1T + bias1))
// MFMA, tile M=32 x N=64 (313 blocks), register-prefetch pipeline
// ---------------------------------------------------------------------------
__global__ __launch_bounds__(256) void hlayer_mfma(
    const unsigned short* __restrict__ xb, const unsigned short* __restrict__ A1b,
    const unsigned short* __restrict__ Wt, const float* __restrict__ bias1,
    unsigned short* __restrict__ hb) {
  __shared__ unsigned short Asb[32][40];
  __shared__ unsigned short Bsb[64][40];
  const int tid = threadIdx.x;
  const int m0 = blockIdx.x * 32;
  const int wv = tid >> 6, lane = tid & 63;
  const int lrow = lane & 15, quad = lane >> 4;
  const int mt = wv >> 1, ntb = (wv & 1) * 2;

  const int brow = tid >> 2, bq = tid & 3;          // B: 64 rows
  const int as_row = (tid & 127) >> 2;              // A: 32 rows (tid<128)
  int gr = m0 + as_row; if (gr >= NN) gr = NN - 1;
  const unsigned short* Arow_x = &xb[(size_t)gr * D1 + bq * 8];
  const unsigned short* Arow_a = &A1b[(size_t)gr * 1024 + bq * 8];
  const unsigned short* Bp = &Wt[(size_t)brow * 1152 + bq * 8];

  uint4 ra0, ra1, rb0, rb1;

#define H_LOAD(ra, rb, c)                                                    \
  { int kb = (c) * 32;                                                       \
    if (tid < 128)                                                           \
      ra = (kb < 128) ? *(const uint4*)(Arow_x + kb)                         \
                      : *(const uint4*)(Arow_a + (kb - 128));                \
    rb = *(const uint4*)(Bp + kb); }

#define H_STORE(ra, rb)                                                      \
  { if (tid < 128) *(uint4*)&Asb[as_row][bq * 8] = ra;                       \
    *(uint4*)&Bsb[brow][bq * 8] = rb; }

#define H_COMPUTE()                                                          \
  { short8 af = *(const short8*)&Asb[mt * 16 + lrow][quad * 8];              \
    _Pragma("unroll")                                                        \
    for (int ntl = 0; ntl < 2; ntl++) {                                      \
      short8 bfr = *(const short8*)&Bsb[(ntb + ntl) * 16 + lrow][quad * 8];  \
      acc[ntl] = __builtin_amdgcn_mfma_f32_16x16x32_bf16(af, bfr, acc[ntl], 0, 0, 0); \
    } }

  float4e acc[2];
#pragma unroll
  for (int i = 0; i < 2; i++) { acc[i][0]=0.f; acc[i][1]=0.f; acc[i][2]=0.f; acc[i][3]=0.f; }

  H_LOAD(ra0, rb0, 0);
  for (int c = 0; c < 36; c += 2) {
    H_STORE(ra0, rb0);
    __syncthreads();
    if (c + 1 < 36) H_LOAD(ra1, rb1, c + 1);
    H_COMPUTE();
    __syncthreads();
    H_STORE(ra1, rb1);
    __syncthreads();
    if (c + 2 < 36) H_LOAD(ra0, rb0, c + 2);
    H_COMPUTE();
    __syncthreads();
  }

#pragma unroll
  for (int ntl = 0; ntl < 2; ntl++) {
    int col = (ntb + ntl) * 16 + lrow;
    float bv = bias1[col];
#pragma unroll
    for (int r = 0; r < 4; r++) {
      int row = m0 + mt * 16 + quad * 4 + r;
      if (row < NN)
        hb[(size_t)row * D2 + col] = f2bf(fmaxf(acc[ntl][r] + bv, 0.f));
    }
  }
}

// ---------------------------------------------------------------------------
// out: out = [hb|A2b](K=576) @ Wc2T + bias2
// MFMA, tile M=32 x N=32 (313 blocks), register-prefetch pipeline
// ---------------------------------------------------------------------------
__global__ __launch_bounds__(256) void out_mfma(
    const unsigned short* __restrict__ hb, const unsigned short* __restrict__ A2b,
    const unsigned short* __restrict__ Wt, const float* __restrict__ bias2,
    float* __restrict__ out) {
  __shared__ unsigned short Asb[32][40];
  __shared__ unsigned short Bsb[32][40];
  const int tid = threadIdx.x;
  const int m0 = blockIdx.x * 32;
  const int wv = tid >> 6, lane = tid & 63;
  const int lrow = lane & 15, quad = lane >> 4;
  const int mt = wv >> 1, nt = wv & 1;

  const int srow = (tid & 127) >> 2, sq = tid & 3;  // 32 rows per half
  int gr = m0 + srow; if (gr >= NN) gr = NN - 1;
  const unsigned short* Arow_h = &hb[(size_t)gr * D2 + sq * 8];
  const unsigned short* Arow_a = &A2b[(size_t)gr * 512 + sq * 8];
  const unsigned short* Bp = &Wt[(size_t)srow * 576 + sq * 8];

  uint4 r0, r1;

#define O_LOAD(rg, c)                                                        \
  { int kb = (c) * 32;                                                       \
    if (tid < 128)                                                           \
      rg = (kb < 64) ? *(const uint4*)(Arow_h + kb)                          \
                     : *(const uint4*)(Arow_a + (kb - 64));                  \
    else                                                                     \
      rg = *(const uint4*)(Bp + kb); }

#define O_STORE(rg)                                                          \
  { if (tid < 128) *(uint4*)&Asb[srow][sq * 8] = rg;                         \
    else           *(uint4*)&Bsb[srow][sq * 8] = rg; }

#define O_COMPUTE()                                                          \
  { short8 af = *(const short8*)&Asb[mt * 16 + lrow][quad * 8];              \
    short8 bfr = *(const short8*)&Bsb[nt * 16 + lrow][quad * 8];             \
    acc = __builtin_amdgcn_mfma_f32_16x16x32_bf16(af, bfr, acc, 0, 0, 0); }

  float4e acc;
  acc[0]=0.f; acc[1]=0.f; acc[2]=0.f; acc[3]=0.f;

  O_LOAD(r0, 0);
  for (int c = 0; c < 18; c += 2) {
    O_STORE(r0);
    __syncthreads();
    if (c + 1 < 18) O_LOAD(r1, c + 1);
    O_COMPUTE();
    __syncthreads();
    O_STORE(r1);
    __syncthreads();
    if (c + 2 < 18) O_LOAD(r0, c + 2);
    O_COMPUTE();
    __syncthreads();
  }

  int col = nt * 16 + lrow;
  if (col < D3) {
    float bv = bias2[col];
#pragma unroll
    for (int r = 0; r < 4; r++) {
      int row = m0 + mt * 16 + quad * 4 + r;
      if (row < NN)
        out[(size_t)row * D3 + col] = acc[r] + bv;
    }
  }
}

// ---------------------------------------------------------------------------
extern "C" void kernel_launch(void* const* d_in, const int* in_sizes, int n_in,
                              void* d_out, int out_size, void* d_ws,
                              size_t ws_size, hipStream_t stream) {
  const float* x_drug = (const float*)d_in[0];
  const float* drug_w = (const float*)d_in[1];
  const int*   ei     = (const int*)d_in[2];
  const float* basis1 = (const float*)d_in[3];
  const float* comp1  = (const float*)d_in[4];
  const float* root1  = (const float*)d_in[5];
  const float* bias1  = (const float*)d_in[6];
  const float* basis2 = (const float*)d_in[7];
  const float* comp2  = (const float*)d_in[8];
  const float* root2  = (const float*)d_in[9];
  const float* bias2  = (const float*)d_in[10];
  float* out = (float*)d_out;

  float* ws = (float*)d_ws;
  int*   deg  = (int*)ws;                          // 1,000,000
  int*   cnt  = deg + 1000000;                     // 10,016
  int*   off  = cnt + 10016;                       // 10,016
  int*   cur  = off + 10016;                       // 10,016
  int*   rec  = cur + 10016;                       // 500,000
  float* esc  = (float*)(rec + 500000);            // 500,000
  unsigned short* xb   = (unsigned short*)(esc + 500000);          // 640,000 f
  unsigned short* hb   = (unsigned short*)((float*)xb + 640000);   // 320,000 f
  unsigned short* Btw  = (unsigned short*)((float*)hb + 320000);   // 131,072 f
  unsigned short* Wc1T = (unsigned short*)((float*)Btw + 131072);  // 36,864 f
  unsigned short* Wc2T = (unsigned short*)((float*)Wc1T + 36864);  // 9,216 f
  float* R1 = (float*)Wc2T + 9216;                 // 5,120,000 floats shared
  float* xp = R1;                                  // 4 x 1,280,000 fp32 partials
  unsigned short* A1b = (unsigned short*)R1;       // aliases xp (after reduce)
  unsigned short* A2b = (unsigned short*)R1;       // aliases A1b (after hlayer)

  // CSR build (zero_deg replaces hipMemsetAsync -> rocclr fill was 46us/iter)
  zero_deg_kernel<<<(NN * RR / 4 + 255) / 256, 256, 0, stream>>>((int4*)deg);
  deg_kernel<<<(NE + 255) / 256, 256, 0, stream>>>(ei, deg);
  cnt_kernel<<<(NN + 255) / 256, 256, 0, stream>>>(deg, cnt);
  scan_kernel<<<1, 1024, 0, stream>>>(cnt, off, cur);
  scatter_kernel<<<(NE + 255) / 256, 256, 0, stream>>>(ei, deg, cur, rec, esc);

  // weights
  wtrans_kernel<<<(128 * 2048 + 255) / 256, 256, 0, stream>>>(drug_w, Btw);
  wc1t_kernel<<<(64 * 1152 + 255) / 256, 256, 0, stream>>>(root1, basis1, Wc1T);
  wc2t_kernel<<<(32 * 576 + 255) / 256, 256, 0, stream>>>(root2, basis2, Wc2T);

  // x = x_drug @ drug_w (bf16 MFMA, K-split 4 + reduce)
  gemm0_mfma<<<dim3(313, 4), 256, 0, stream>>>(x_drug, Btw, xp);
  reduce_kernel<<<(NN * D1 / 4 + 255) / 256, 256, 0, stream>>>(xp, xb);

  // layer 1
  agg1e_kernel<<<(NN + 3) / 4, 256, 0, stream>>>(xb, off, rec, esc, comp1, A1b);
  hlayer_mfma<<<(NN + 31) / 32, 256, 0, stream>>>(xb, A1b, Wc1T, bias1, hb);

  // layer 2
  agg2e_kernel<<<(NN + 3) / 4, 256, 0, stream>>>(hb, off, rec, esc, comp2, A2b);
  out_mfma<<<(NN + 31) / 32, 256, 0, stream>>>(hb, A2b, Wc2T, bias2, out);
}

// Round 3
// 191.001 us; speedup vs baseline: 1.0602x; 1.0602x over previous
//
#include <hip/hip_runtime.h>

#define NN 10000    // nodes
#define RR 100      // relations
#define EE 5000     // edges per relation
#define D0 2048
#define D1 128
#define D2 64
#define D3 20
#define NE (RR*EE)  // 500000 edges total

using short8  = __attribute__((ext_vector_type(8))) short;
using float4e = __attribute__((ext_vector_type(4))) float;

__device__ __forceinline__ unsigned short f2bf(float f) {
  unsigned int u = __float_as_uint(f);
  unsigned int r = u + 0x7fffu + ((u >> 16) & 1u);   // RNE
  return (unsigned short)(r >> 16);
}
__device__ __forceinline__ float bf2f(unsigned short u) {
  return __uint_as_float(((unsigned int)u) << 16);
}
__device__ __forceinline__ unsigned int pk2(float lo, float hi) {
  return ((unsigned int)f2bf(hi) << 16) | (unsigned int)f2bf(lo);
}

// ---------------------------------------------------------------------------
// prep: fused {zero deg, wtrans, wc1t, wc2t} — 4 independent kernels in one
// dispatch (block-range switch). Probes the launch-gap theory (13->10).
// ---------------------------------------------------------------------------
#define ZBLK 977            // 250,000 int4 zeros
#define WTBLK 1024          // 262,144 elems
#define W1BLK 288           // 73,728 elems
#define W2BLK 72            // 18,432 elems
__global__ __launch_bounds__(256) void prep_kernel(
    const float* __restrict__ W, const float* __restrict__ root1,
    const float* __restrict__ basis1, const float* __restrict__ root2,
    const float* __restrict__ basis2, int4* __restrict__ deg4,
    unsigned short* __restrict__ Btw, unsigned short* __restrict__ Wc1T,
    unsigned short* __restrict__ Wc2T) {
  const int b = blockIdx.x, tid = threadIdx.x;
  if (b < ZBLK) {
    int i = b * 256 + tid;
    if (i < (NN * RR) / 4) deg4[i] = make_int4(0, 0, 0, 0);
  } else if (b < ZBLK + WTBLK) {
    int idx = (b - ZBLK) * 256 + tid;                 // 128*2048, exact
    int n = idx >> 11, k = idx & 2047;
    Btw[idx] = f2bf(W[(size_t)k * 128 + n]);
  } else if (b < ZBLK + WTBLK + W1BLK) {
    int idx = (b - ZBLK - WTBLK) * 256 + tid;         // 64*1152, exact
    int o = idx / 1152, j = idx - o * 1152;
    float v = (j < 128) ? root1[j * 64 + o] : basis1[(j - 128) * 64 + o];
    Wc1T[idx] = f2bf(v);
  } else {
    int idx = (b - ZBLK - WTBLK - W1BLK) * 256 + tid; // 32*576, exact
    int c = idx / 576, j = idx - c * 576;
    float v = 0.f;
    if (c < 20) v = (j < 64) ? root2[j * 20 + c] : basis2[(j - 64) * 20 + c];
    Wc2T[idx] = f2bf(v);
  }
}

// ---------------------------------------------------------------------------
// CSR build
// ---------------------------------------------------------------------------
__global__ void deg_kernel(const int* __restrict__ ei, int* __restrict__ deg) {
  int gid = blockIdx.x * 256 + threadIdx.x;
  if (gid >= NE) return;
  int r = gid / EE, e = gid - r * EE;
  int d = ei[r * 2 * EE + EE + e];
  atomicAdd(&deg[r * NN + d], 1);
}

__global__ void cnt_kernel(const int* __restrict__ deg, int* __restrict__ cnt) {
  int n = blockIdx.x * 256 + threadIdx.x;
  if (n >= NN) return;
  int s = 0;
  for (int r = 0; r < RR; r++) s += deg[r * NN + n];
  cnt[n] = s;
}

__global__ __launch_bounds__(1024) void scan_kernel(const int* __restrict__ cnt,
                                                    int* __restrict__ off,
                                                    int* __restrict__ cur) {
  __shared__ int wsum[16];
  __shared__ int carry_s;
  const int tid = threadIdx.x;
  const int wv = tid >> 6, lane = tid & 63;
  if (tid == 0) carry_s = 0;
  __syncthreads();
  for (int base = 0; base < NN; base += 1024) {
    int i = base + tid;
    int v = (i < NN) ? cnt[i] : 0;
    int s = v;
#pragma unroll
    for (int d = 1; d < 64; d <<= 1) {
      int t = __shfl_up(s, d, 64);
      if (lane >= d) s += t;
    }
    if (lane == 63) wsum[wv] = s;
    __syncthreads();
    if (wv == 0) {
      int w = (lane < 16) ? wsum[lane] : 0;
#pragma unroll
      for (int d = 1; d < 16; d <<= 1) {
        int t = __shfl_up(w, d, 64);
        if (lane >= d) w += t;
      }
      if (lane < 16) wsum[lane] = w;
    }
    __syncthreads();
    int excl = carry_s + (wv > 0 ? wsum[wv - 1] : 0) + s - v;
    if (i < NN) { off[i] = excl; cur[i] = excl; }
    __syncthreads();
    if (tid == 1023) carry_s += wsum[15];
    __syncthreads();
  }
  if (tid == 0) off[NN] = carry_s;
}

// rec = (r<<14)|src, esc = 1/max(deg,1)
__global__ void scatter_kernel(const int* __restrict__ ei,
                               const int* __restrict__ deg,
                               int* __restrict__ cur, int* __restrict__ rec,
                               float* __restrict__ esc) {
  int gid = blockIdx.x * 256 + threadIdx.x;
  if (gid >= NE) return;
  int r = gid / EE, e = gid - r * EE;
  int s = ei[r * 2 * EE + e];
  int d = ei[r * 2 * EE + EE + e];
  int p = atomicAdd(&cur[d], 1);
  rec[p] = (r << 14) | s;
  esc[p] = 1.0f / fmaxf((float)deg[r * NN + d], 1.0f);
}

// ---------------------------------------------------------------------------
// gemm0: xp[ks] = x_drug[:, ks*512:+512] @ drug_w[ks*512:,:]  (K-split 4)
// bf16 MFMA 16x16x32; tile M=32, N=128, BK=64; double-buffered XOR-swizzled
// LDS; 2-DEEP register prefetch: iter c issues loads for step c+2, stores
// step c+1, computes step c -> compiler emits counted vmcnt (waits only the
// older load set), never drains the pipe (T4). launch_bounds(256,4) keeps
// VGPR<=128 so the LDS limit (4 blocks/CU, 16 waves/CU) is reachable.
// ---------------------------------------------------------------------------
__global__ __launch_bounds__(256, 4) void gemm0_mfma(
    const float* __restrict__ A, const unsigned short* __restrict__ Btw,
    float* __restrict__ xp) {
  __shared__ __align__(16) unsigned short Asb[2][32 * 64];    // 2 x 4 KB
  __shared__ __align__(16) unsigned short Bsb[2][128 * 64];   // 2 x 16 KB
  const int tid = threadIdx.x;
  const int m0 = blockIdx.x * 32;
  const int ks = blockIdx.y;
  const int wv = tid >> 6, lane = tid & 63;
  const int lrow = lane & 15, quad = lane >> 4;
  const int mt = wv >> 1;           // which 16-row half of the 32-row tile
  const int nh = (wv & 1) * 4;      // 4 n-tiles of 16 cols (64-col half)

  const int ar = tid >> 3, ag = tid & 7;
  int gra = m0 + ar; if (gra >= NN) gra = NN - 1;
  const float* Ap = &A[(size_t)gra * D0 + ks * 512 + ag * 4];
  const int asw = (ar & 7) << 4;
  const int aw0 = (ar * 128 + ((ag * 8) ^ asw)) >> 1;        // ushort idx
  const int aw1 = (ar * 128 + ((64 + ag * 8) ^ asw)) >> 1;

  const int br = tid >> 1, bh = tid & 1;
  const unsigned short* Bp = &Btw[(size_t)br * D0 + ks * 512 + bh * 8];
  const int bsw = (br & 7) << 4;
  int bw[4];
#pragma unroll
  for (int j = 0; j < 4; j++)
    bw[j] = (br * 128 + ((bh * 16 + j * 32) ^ bsw)) >> 1;

  // two in-flight register sets (X = even steps, Y = odd steps)
  float4 Xa0, Xa1, Ya0, Ya1;
  uint4 Xb0, Xb1, Xb2, Xb3, Yb0, Yb1, Yb2, Yb3;

#define G0_LOADG(P, c)                                  \
  { P##a0 = *(const float4*)(Ap + (c) * 64);            \
    P##a1 = *(const float4*)(Ap + (c) * 64 + 32);       \
    P##b0 = *(const uint4*)(Bp + (c) * 64);             \
    P##b1 = *(const uint4*)(Bp + (c) * 64 + 16);        \
    P##b2 = *(const uint4*)(Bp + (c) * 64 + 32);        \
    P##b3 = *(const uint4*)(Bp + (c) * 64 + 48); }

#define G0_STOREL(buf, P)                                               \
  { uint2 p0, p1;                                                       \
    p0.x = pk2(P##a0.x, P##a0.y); p0.y = pk2(P##a0.z, P##a0.w);         \
    p1.x = pk2(P##a1.x, P##a1.y); p1.y = pk2(P##a1.z, P##a1.w);         \
    *(uint2*)&Asb[buf][aw0] = p0;                                       \
    *(uint2*)&Asb[buf][aw1] = p1;                                       \
    *(uint4*)&Bsb[buf][bw[0]] = P##b0;                                  \
    *(uint4*)&Bsb[buf][bw[1]] = P##b1;                                  \
    *(uint4*)&Bsb[buf][bw[2]] = P##b2;                                  \
    *(uint4*)&Bsb[buf][bw[3]] = P##b3; }

#define G0_COMPUTE(buf)                                                 \
  { const int arow = mt * 16 + lrow;                                    \
    const int aswz = (arow & 7) << 4;                                   \
    _Pragma("unroll")                                                   \
    for (int kk = 0; kk < 2; kk++) {                                    \
      short8 af = *(const short8*)&Asb[buf][(arow * 128 + ((quad * 16 + kk * 64) ^ aswz)) >> 1]; \
      _Pragma("unroll")                                                 \
      for (int nt = 0; nt < 4; nt++) {                                  \
        const int brow = (nh + nt) * 16 + lrow;                         \
        short8 bfr = *(const short8*)&Bsb[buf][(brow * 128 + ((quad * 16 + kk * 64) ^ ((brow & 7) << 4))) >> 1]; \
        acc[nt] = __builtin_amdgcn_mfma_f32_16x16x32_bf16(af, bfr, acc[nt], 0, 0, 0); \
      }                                                                 \
    } }

  float4e acc[4];
#pragma unroll
  for (int i = 0; i < 4; i++) { acc[i][0]=0.f; acc[i][1]=0.f; acc[i][2]=0.f; acc[i][3]=0.f; }

  // prologue: steps 0 and 1 in flight; stage step 0
  G0_LOADG(X, 0);
  G0_LOADG(Y, 1);
  G0_STOREL(0, X);
  __syncthreads();

  // iter c: load step c+2 (into the set freed by last iter's store),
  // compute step c, store step c+1 into the other LDS buffer.
#pragma unroll
  for (int c = 0; c < 8; c++) {
    if (c < 6) {
      if ((c & 1) == 0) { G0_LOADG(X, c + 2); } else { G0_LOADG(Y, c + 2); }
    }
    G0_COMPUTE(c & 1);
    if (c < 7) {
      if ((c & 1) == 0) { G0_STOREL(1, Y); } else { G0_STOREL(0, X); }
    }
    __syncthreads();
  }

#pragma unroll
  for (int nt = 0; nt < 4; nt++) {
    const int col = (nh + nt) * 16 + lrow;
#pragma unroll
    for (int r = 0; r < 4; r++) {
      const int row = m0 + mt * 16 + quad * 4 + r;
      if (row < NN)
        xp[(size_t)ks * (NN * D1) + (size_t)row * D1 + col] = acc[nt][r];
    }
  }
}

// xb = bf16(xp0+xp1+xp2+xp3)
__global__ void reduce_kernel(const float* __restrict__ xp,
                              unsigned short* __restrict__ xb) {
  int idx = (blockIdx.x * 256 + threadIdx.x) * 4;
  if (idx >= NN * D1) return;
  float4 a = *(const float4*)&xp[idx];
  float4 b = *(const float4*)&xp[NN * D1 + idx];
  float4 c = *(const float4*)&xp[2 * NN * D1 + idx];
  float4 d = *(const float4*)&xp[3 * NN * D1 + idx];
  ushort4 o;
  o.x = f2bf(a.x + b.x + c.x + d.x); o.y = f2bf(a.y + b.y + c.y + d.y);
  o.z = f2bf(a.z + b.z + c.z + d.z); o.w = f2bf(a.w + b.w + c.w + d.w);
  *(ushort4*)&xb[idx] = o;
}

// ---------------------------------------------------------------------------
// agg1e: A1b[n, b*128+i] = bf16( sum_{e->n} esc_e*comp1[r_e,b]*x[src_e,i] )
// one wave per node; lane holds 2 of 128 channels; 4-edge unroll
// ---------------------------------------------------------------------------
__global__ __launch_bounds__(256) void agg1e_kernel(
    const unsigned short* __restrict__ xb, const int* __restrict__ off,
    const int* __restrict__ rec, const float* __restrict__ esc,
    const float* __restrict__ comp, unsigned short* __restrict__ A1b) {
  __shared__ float s_comp[RR * 8];
  const int tid = threadIdx.x;
  for (int i = tid; i < RR * 8; i += 256) s_comp[i] = comp[i];
  __syncthreads();
  const int wv = tid >> 6, lane = tid & 63;
  const int n = blockIdx.x * 4 + wv;
  if (n >= NN) return;
  float acc[8][2];
#pragma unroll
  for (int b = 0; b < 8; b++) { acc[b][0] = 0.f; acc[b][1] = 0.f; }
  const int beg = off[n], end = off[n + 1];
  int idx = beg;
  for (; idx + 3 < end; idx += 4) {
    int rc[4]; float sc[4]; unsigned int xv[4];
#pragma unroll
    for (int u = 0; u < 4; u++) {
      rc[u] = rec[idx + u];
      sc[u] = esc[idx + u];
    }
#pragma unroll
    for (int u = 0; u < 4; u++)
      xv[u] = *(const unsigned int*)&xb[(size_t)(rc[u] & 16383) * D1 + lane * 2];
#pragma unroll
    for (int u = 0; u < 4; u++) {
      const float* cb = &s_comp[(rc[u] >> 14) * 8];
      float x0 = __uint_as_float((xv[u] & 0xffffu) << 16);
      float x1 = __uint_as_float(xv[u] & 0xffff0000u);
#pragma unroll
      for (int b = 0; b < 8; b++) {
        float w = sc[u] * cb[b];
        acc[b][0] += w * x0;
        acc[b][1] += w * x1;
      }
    }
  }
  for (; idx < end; idx++) {
    int rc = rec[idx];
    float sc = esc[idx];
    unsigned int xv = *(const unsigned int*)&xb[(size_t)(rc & 16383) * D1 + lane * 2];
    const float* cb = &s_comp[(rc >> 14) * 8];
    float x0 = __uint_as_float((xv & 0xffffu) << 16);
    float x1 = __uint_as_float(xv & 0xffff0000u);
#pragma unroll
    for (int b = 0; b < 8; b++) {
      float w = sc * cb[b];
      acc[b][0] += w * x0;
      acc[b][1] += w * x1;
    }
  }
#pragma unroll
  for (int b = 0; b < 8; b++) {
    ushort2 o; o.x = f2bf(acc[b][0]); o.y = f2bf(acc[b][1]);
    *(ushort2*)&A1b[(size_t)n * 1024 + b * 128 + lane * 2] = o;
  }
}

// ---------------------------------------------------------------------------
// agg2e: A2b[n, b*64+i] = bf16( sum_{e->n} esc_e*comp2[r_e,b]*h[src_e,i] )
// ---------------------------------------------------------------------------
__global__ __launch_bounds__(256) void agg2e_kernel(
    const unsigned short* __restrict__ hb, const int* __restrict__ off,
    const int* __restrict__ rec, const float* __restrict__ esc,
    const float* __restrict__ comp, unsigned short* __restrict__ A2b) {
  __shared__ float s_comp[RR * 8];
  const int tid = threadIdx.x;
  for (int i = tid; i < RR * 8; i += 256) s_comp[i] = comp[i];
  __syncthreads();
  const int wv = tid >> 6, lane = tid & 63;
  const int n = blockIdx.x * 4 + wv;
  if (n >= NN) return;
  float acc[8];
#pragma unroll
  for (int b = 0; b < 8; b++) acc[b] = 0.f;
  const int beg = off[n], end = off[n + 1];
  int idx = beg;
  for (; idx + 3 < end; idx += 4) {
    int rc[4]; float sc[4]; float hv[4];
#pragma unroll
    for (int u = 0; u < 4; u++) {
      rc[u] = rec[idx + u];
      sc[u] = esc[idx + u];
    }
#pragma unroll
    for (int u = 0; u < 4; u++)
      hv[u] = bf2f(hb[(size_t)(rc[u] & 16383) * D2 + lane]);
#pragma unroll
    for (int u = 0; u < 4; u++) {
      const float* cb = &s_comp[(rc[u] >> 14) * 8];
#pragma unroll
      for (int b = 0; b < 8; b++) acc[b] += sc[u] * cb[b] * hv[u];
    }
  }
  for (; idx < end; idx++) {
    int rc = rec[idx];
    float sc = esc[idx];
    float hv = bf2f(hb[(size_t)(rc & 16383) * D2 + lane]);
    const float* cb = &s_comp[(rc >> 14) * 8];
#pragma unroll
    for (int b = 0; b < 8; b++) acc[b] += sc * cb[b] * hv;
  }
#pragma unroll
  for (int b = 0; b < 8; b++)
    A2b[(size_t)n * 512 + b * 64 + lane] = f2bf(acc[b]);
}

// ---------------------------------------------------------------------------
// hlayer: hb = bf16(relu([xb|A1b](K=1152) @ Wc1T + bias1))
// MFMA, tile M=32 x N=64 (313 blocks), register-prefetch pipeline
// ---------------------------------------------------------------------------
__global__ __launch_bounds__(256) void hlayer_mfma(
    const unsigned short* __restrict__ xb, const unsigned short* __restrict__ A1b,
    const unsigned short* __restrict__ Wt, const float* __restrict__ bias1,
    unsigned short* __restrict__ hb) {
  __shared__ unsigned short Asb[32][40];
  __shared__ unsigned short Bsb[64][40];
  const int tid = threadIdx.x;
  const int m0 = blockIdx.x * 32;
  const int wv = tid >> 6, lane = tid & 63;
  const int lrow = lane & 15, quad = lane >> 4;
  const int mt = wv >> 1, ntb = (wv & 1) * 2;

  const int brow = tid >> 2, bq = tid & 3;          // B: 64 rows
  const int as_row = (tid & 127) >> 2;              // A: 32 rows (tid<128)
  int gr = m0 + as_row; if (gr >= NN) gr = NN - 1;
  const unsigned short* Arow_x = &xb[(size_t)gr * D1 + bq * 8];
  const unsigned short* Arow_a = &A1b[(size_t)gr * 1024 + bq * 8];
  const unsigned short* Bp = &Wt[(size_t)brow * 1152 + bq * 8];

  uint4 ra0, ra1, rb0, rb1;

#define H_LOAD(ra, rb, c)                                                    \
  { int kb = (c) * 32;                                                       \
    if (tid < 128)                                                           \
      ra = (kb < 128) ? *(const uint4*)(Arow_x + kb)                         \
                      : *(const uint4*)(Arow_a + (kb - 128));                \
    rb = *(const uint4*)(Bp + kb); }

#define H_STORE(ra, rb)                                                      \
  { if (tid < 128) *(uint4*)&Asb[as_row][bq * 8] = ra;                       \
    *(uint4*)&Bsb[brow][bq * 8] = rb; }

#define H_COMPUTE()                                                          \
  { short8 af = *(const short8*)&Asb[mt * 16 + lrow][quad * 8];              \
    _Pragma("unroll")                                                        \
    for (int ntl = 0; ntl < 2; ntl++) {                                      \
      short8 bfr = *(const short8*)&Bsb[(ntb + ntl) * 16 + lrow][quad * 8];  \
      acc[ntl] = __builtin_amdgcn_mfma_f32_16x16x32_bf16(af, bfr, acc[ntl], 0, 0, 0); \
    } }

  float4e acc[2];
#pragma unroll
  for (int i = 0; i < 2; i++) { acc[i][0]=0.f; acc[i][1]=0.f; acc[i][2]=0.f; acc[i][3]=0.f; }

  H_LOAD(ra0, rb0, 0);
  for (int c = 0; c < 36; c += 2) {
    H_STORE(ra0, rb0);
    __syncthreads();
    if (c + 1 < 36) H_LOAD(ra1, rb1, c + 1);
    H_COMPUTE();
    __syncthreads();
    H_STORE(ra1, rb1);
    __syncthreads();
    if (c + 2 < 36) H_LOAD(ra0, rb0, c + 2);
    H_COMPUTE();
    __syncthreads();
  }

#pragma unroll
  for (int ntl = 0; ntl < 2; ntl++) {
    int col = (ntb + ntl) * 16 + lrow;
    float bv = bias1[col];
#pragma unroll
    for (int r = 0; r < 4; r++) {
      int row = m0 + mt * 16 + quad * 4 + r;
      if (row < NN)
        hb[(size_t)row * D2 + col] = f2bf(fmaxf(acc[ntl][r] + bv, 0.f));
    }
  }
}

// ---------------------------------------------------------------------------
// out: out = [hb|A2b](K=576) @ Wc2T + bias2
// MFMA, tile M=32 x N=32 (313 blocks), register-prefetch pipeline
// ---------------------------------------------------------------------------
__global__ __launch_bounds__(256) void out_mfma(
    const unsigned short* __restrict__ hb, const unsigned short* __restrict__ A2b,
    const unsigned short* __restrict__ Wt, const float* __restrict__ bias2,
    float* __restrict__ out) {
  __shared__ unsigned short Asb[32][40];
  __shared__ unsigned short Bsb[32][40];
  const int tid = threadIdx.x;
  const int m0 = blockIdx.x * 32;
  const int wv = tid >> 6, lane = tid & 63;
  const int lrow = lane & 15, quad = lane >> 4;
  const int mt = wv >> 1, nt = wv & 1;

  const int srow = (tid & 127) >> 2, sq = tid & 3;  // 32 rows per half
  int gr = m0 + srow; if (gr >= NN) gr = NN - 1;
  const unsigned short* Arow_h = &hb[(size_t)gr * D2 + sq * 8];
  const unsigned short* Arow_a = &A2b[(size_t)gr * 512 + sq * 8];
  const unsigned short* Bp = &Wt[(size_t)srow * 576 + sq * 8];

  uint4 r0, r1;

#define O_LOAD(rg, c)                                                        \
  { int kb = (c) * 32;                                                       \
    if (tid < 128)                                                           \
      rg = (kb < 64) ? *(const uint4*)(Arow_h + kb)                          \
                     : *(const uint4*)(Arow_a + (kb - 64));                  \
    else                                                                     \
      rg = *(const uint4*)(Bp + kb); }

#define O_STORE(rg)                                                          \
  { if (tid < 128) *(uint4*)&Asb[srow][sq * 8] = rg;                         \
    else           *(uint4*)&Bsb[srow][sq * 8] = rg; }

#define O_COMPUTE()                                                          \
  { short8 af = *(const short8*)&Asb[mt * 16 + lrow][quad * 8];              \
    short8 bfr = *(const short8*)&Bsb[nt * 16 + lrow][quad * 8];             \
    acc = __builtin_amdgcn_mfma_f32_16x16x32_bf16(af, bfr, acc, 0, 0, 0); }

  float4e acc;
  acc[0]=0.f; acc[1]=0.f; acc[2]=0.f; acc[3]=0.f;

  O_LOAD(r0, 0);
  for (int c = 0; c < 18; c += 2) {
    O_STORE(r0);
    __syncthreads();
    if (c + 1 < 18) O_LOAD(r1, c + 1);
    O_COMPUTE();
    __syncthreads();
    O_STORE(r1);
    __syncthreads();
    if (c + 2 < 18) O_LOAD(r0, c + 2);
    O_COMPUTE();
    __syncthreads();
  }

  int col = nt * 16 + lrow;
  if (col < D3) {
    float bv = bias2[col];
#pragma unroll
    for (int r = 0; r < 4; r++) {
      int row = m0 + mt * 16 + quad * 4 + r;
      if (row < NN)
        out[(size_t)row * D3 + col] = acc[r] + bv;
    }
  }
}

// ---------------------------------------------------------------------------
extern "C" void kernel_launch(void* const* d_in, const int* in_sizes, int n_in,
                              void* d_out, int out_size, void* d_ws,
                              size_t ws_size, hipStream_t stream) {
  const float* x_drug = (const float*)d_in[0];
  const float* drug_w = (const float*)d_in[1];
  const int*   ei     = (const int*)d_in[2];
  const float* basis1 = (const float*)d_in[3];
  const float* comp1  = (const float*)d_in[4];
  const float* root1  = (const float*)d_in[5];
  const float* bias1  = (const float*)d_in[6];
  const float* basis2 = (const float*)d_in[7];
  const float* comp2  = (const float*)d_in[8];
  const float* root2  = (const float*)d_in[9];
  const float* bias2  = (const float*)d_in[10];
  float* out = (float*)d_out;

  float* ws = (float*)d_ws;
  int*   deg  = (int*)ws;                          // 1,000,000
  int*   cnt  = deg + 1000000;                     // 10,016
  int*   off  = cnt + 10016;                       // 10,016
  int*   cur  = off + 10016;                       // 10,016
  int*   rec  = cur + 10016;                       // 500,000
  float* esc  = (float*)(rec + 500000);            // 500,000
  unsigned short* xb   = (unsigned short*)(esc + 500000);          // 640,000 f
  unsigned short* hb   = (unsigned short*)((float*)xb + 640000);   // 320,000 f
  unsigned short* Btw  = (unsigned short*)((float*)hb + 320000);   // 131,072 f
  unsigned short* Wc1T = (unsigned short*)((float*)Btw + 131072);  // 36,864 f
  unsigned short* Wc2T = (unsigned short*)((float*)Wc1T + 36864);  // 9,216 f
  float* R1 = (float*)Wc2T + 9216;                 // 5,120,000 floats shared
  float* xp = R1;                                  // 4 x 1,280,000 fp32 partials
  unsigned short* A1b = (unsigned short*)R1;       // aliases xp (after reduce)
  unsigned short* A2b = (unsigned short*)R1;       // aliases A1b (after hlayer)

  // fused prep: zero deg + all weight transposes (one dispatch)
  prep_kernel<<<ZBLK + WTBLK + W1BLK + W2BLK, 256, 0, stream>>>(
      drug_w, root1, basis1, root2, basis2, (int4*)deg, Btw, Wc1T, Wc2T);

  // CSR build
  deg_kernel<<<(NE + 255) / 256, 256, 0, stream>>>(ei, deg);
  cnt_kernel<<<(NN + 255) / 256, 256, 0, stream>>>(deg, cnt);
  scan_kernel<<<1, 1024, 0, stream>>>(cnt, off, cur);
  scatter_kernel<<<(NE + 255) / 256, 256, 0, stream>>>(ei, deg, cur, rec, esc);

  // x = x_drug @ drug_w (bf16 MFMA, K-split 4 + reduce)
  gemm0_mfma<<<dim3(313, 4), 256, 0, stream>>>(x_drug, Btw, xp);
  reduce_kernel<<<(NN * D1 / 4 + 255) / 256, 256, 0, stream>>>(xp, xb);

  // layer 1
  agg1e_kernel<<<(NN + 3) / 4, 256, 0, stream>>>(xb, off, rec, esc, comp1, A1b);
  hlayer_mfma<<<(NN + 31) / 32, 256, 0, stream>>>(xb, A1b, Wc1T, bias1, hb);

  // layer 2
  agg2e_kernel<<<(NN + 3) / 4, 256, 0, stream>>>(hb, off, rec, esc, comp2, A2b);
  out_mfma<<<(NN + 31) / 32, 256, 0, stream>>>(hb, A2b, Wc2T, bias2, out);
}